// Round 2
// baseline (328.965 us; speedup 1.0000x reference)
//
#include <hip/hip_runtime.h>

typedef unsigned short u16;
typedef unsigned int u32;
typedef short bf16x8 __attribute__((ext_vector_type(8)));
typedef float f32x16 __attribute__((ext_vector_type(16)));

#define BM 128
#define BN 128

// ---------- helpers ----------
__device__ __forceinline__ u16 f2bf(float f) {
    u32 u = __float_as_uint(f);
    u32 r = (u + 0x7fffu + ((u >> 16) & 1u)) >> 16;   // RNE
    return (u16)r;
}

__device__ __forceinline__ void unpack8(uint4 u, float* f) {
    f[0] = __uint_as_float(u.x << 16); f[1] = __uint_as_float(u.x & 0xffff0000u);
    f[2] = __uint_as_float(u.y << 16); f[3] = __uint_as_float(u.y & 0xffff0000u);
    f[4] = __uint_as_float(u.z << 16); f[5] = __uint_as_float(u.z & 0xffff0000u);
    f[6] = __uint_as_float(u.w << 16); f[7] = __uint_as_float(u.w & 0xffff0000u);
}

// async 16B/lane global->LDS (dest = wave-uniform base + lane*16)
__device__ __forceinline__ void gld_lds16(const void* g, void* s) {
    __builtin_amdgcn_global_load_lds(
        (__attribute__((address_space(1))) void*)(g),
        (__attribute__((address_space(3))) void*)(s),
        16, 0, 0);
}

// ---------- merged cast kernel: x (16M f32) + 4 weights (4M f32) -> bf16 ----------
__global__ void cast_all(const float* __restrict__ x,
                         const float* __restrict__ wq, const float* __restrict__ wk,
                         const float* __restrict__ wv, const float* __restrict__ wfc,
                         u16* __restrict__ xb, u16* __restrict__ wqkvb, u16* __restrict__ wfcb) {
    size_t g = (size_t)blockIdx.x * 256 + threadIdx.x;   // float4 index
    const float* s;
    u16* d;
    size_t off;
    if (g < 4194304u) {            // x: 16,777,216 floats = 4,194,304 float4
        s = x; d = xb; off = g;
    } else {
        size_t w = g - 4194304u;   // weights: 4 x 262,144 float4
        int y = (int)(w >> 18);
        off = w & 262143u;
        s = (y == 0) ? wq : (y == 1) ? wk : (y == 2) ? wv : wfc;
        d = (y < 3) ? (wqkvb + (size_t)y * 1048576u) : wfcb;
    }
    float4 v = ((const float4*)s)[off];
    ushort4 o;
    o.x = f2bf(v.x); o.y = f2bf(v.y); o.z = f2bf(v.z); o.w = f2bf(v.w);
    *(ushort4*)(d + off * 4) = o;
}

// ---------- bf16 GEMM: C[M,N] = A[M,K] * B[N,K]^T ----------
// 128x128 tile, BK=64, 256 threads (4 waves, 2x2), 32x32x16 MFMA, 2x2 acc/wave.
// LDS chunks XOR-swizzled (phys_chunk = logical_chunk ^ (row&7)) via the
// *global* source address of global_load_lds, so b128 frag reads are
// conflict-free (verified SQ_LDS_BANK_CONFLICT=0 with the 16x16 variant).
template <int STOREF32>
__global__ __launch_bounds__(256, 2)
void gemm_bt(const u16* __restrict__ A, const u16* __restrict__ B,
             void* __restrict__ C, int M, int N, int K) {
    __shared__ __align__(16) u16 As[BM * 64];
    __shared__ __align__(16) u16 Bs[BN * 64];

    const int tid  = threadIdx.x;
    const int lane = tid & 63;
    const int wave = tid >> 6;
    const int wm = wave >> 1, wn = wave & 1;
    const int bm = blockIdx.y * BM;
    const int bn = blockIdx.x * BN;

    const int srow   = lane >> 3;            // row within 8-row staging group
    const int schunk = (lane & 7) ^ srow;    // xor-swizzled source chunk

    f32x16 acc[2][2];
#pragma unroll
    for (int i = 0; i < 2; ++i)
#pragma unroll
        for (int j = 0; j < 2; ++j)
#pragma unroll
            for (int e = 0; e < 16; ++e) acc[i][j][e] = 0.f;

    const int nkt = K >> 6;
    for (int kt = 0; kt < nkt; ++kt) {
        const int k0 = kt << 6;
        __syncthreads();   // prior compute done reading LDS
#pragma unroll
        for (int j = 0; j < 4; ++j) {
            const int r = wave * 32 + j * 8;
            gld_lds16(A + (size_t)(bm + r + srow) * K + k0 + schunk * 8, &As[r * 64]);
            gld_lds16(B + (size_t)(bn + r + srow) * K + k0 + schunk * 8, &Bs[r * 64]);
        }
        __syncthreads();   // compiler drains vmcnt before barrier
#pragma unroll
        for (int ks = 0; ks < 4; ++ks) {
            const int c = ks * 2 + (lane >> 5);   // 8-elem k-chunk index, k = c*8..c*8+7
            bf16x8 af[2], bfr[2];
#pragma unroll
            for (int i = 0; i < 2; ++i) {
                int m = wm * 64 + i * 32 + (lane & 31);
                af[i] = *(const bf16x8*)&As[m * 64 + ((c ^ (m & 7)) << 3)];
            }
#pragma unroll
            for (int j = 0; j < 2; ++j) {
                int n = wn * 64 + j * 32 + (lane & 31);
                bfr[j] = *(const bf16x8*)&Bs[n * 64 + ((c ^ (n & 7)) << 3)];
            }
#pragma unroll
            for (int i = 0; i < 2; ++i)
#pragma unroll
                for (int j = 0; j < 2; ++j)
                    acc[i][j] = __builtin_amdgcn_mfma_f32_32x32x16_bf16(
                        af[i], bfr[j], acc[i][j], 0, 0, 0);
        }
    }

    // epilogue: 32x32 D layout col=lane&31, row=(reg&3)+8*(reg>>2)+4*(lane>>5)
    const int cc = lane & 31;
    const int r4 = (lane >> 5) * 4;
#pragma unroll
    for (int i = 0; i < 2; ++i) {
#pragma unroll
        for (int j = 0; j < 2; ++j) {
            const int row_base = bm + wm * 64 + i * 32 + r4;
            const int col      = bn + wn * 64 + j * 32 + cc;
#pragma unroll
            for (int r = 0; r < 16; ++r) {
                const int row = row_base + (r & 3) + 8 * (r >> 2);
                float v = acc[i][j][r];
                size_t idx = (size_t)row * N + col;
                if (STOREF32) ((float*)C)[idx] = v;
                else          ((u16*)C)[idx]   = f2bf(v);
            }
        }
    }
}

// ---------- per-token attention: 1 wave = 1 token ----------
// QKV row m: [q(1024) | k(1024) | v(1024)] bf16. 16 heads x 64 dim.
// scores 16x16 over heads axis, softmax over t, O = P @ V -> bf16 [m,1024].
__global__ __launch_bounds__(256)
void attn_kernel(const u16* __restrict__ QKV, u16* __restrict__ O) {
    __shared__ __align__(16) u16 sq[4][3][16 * 72];   // rows padded 64->72
    __shared__ float sp[4][16 * 20];                  // P rows padded 16->20

    const int lane = threadIdx.x & 63;
    const int wave = threadIdx.x >> 6;
    const size_t m = (size_t)blockIdx.x * 4 + wave;
    const u16* base = QKV + m * 3072;

    // stage 6KB/token: 384 16B chunks, 6 per lane, padded LDS layout
#pragma unroll
    for (int c6 = 0; c6 < 6; ++c6) {
        int chunk = c6 * 64 + lane;          // 0..383
        int mat = chunk >> 7;
        int cc  = chunk & 127;
        int row = cc >> 3, pch = cc & 7;
        *(uint4*)&sq[wave][mat][row * 72 + pch * 8] = *(const uint4*)(base + chunk * 8);
    }
    __syncthreads();

    // scores: lane (h = lane&15, g = lane>>4) computes s[h][g*4 .. g*4+3]
    const int h = lane & 15, g = lane >> 4;
    float s[4] = {0.f, 0.f, 0.f, 0.f};
#pragma unroll
    for (int c = 0; c < 8; ++c) {
        uint4 qc = *(const uint4*)&sq[wave][0][h * 72 + c * 8];
        float qf[8]; unpack8(qc, qf);
#pragma unroll
        for (int t4 = 0; t4 < 4; ++t4) {
            int t = g * 4 + t4;
            uint4 kc = *(const uint4*)&sq[wave][1][t * 72 + c * 8];
            float kf[8]; unpack8(kc, kf);
#pragma unroll
            for (int e = 0; e < 8; ++e) s[t4] = fmaf(qf[e], kf[e], s[t4]);
        }
    }
#pragma unroll
    for (int t4 = 0; t4 < 4; ++t4) s[t4] *= 0.125f;   // 1/sqrt(64)

    // softmax over t (row h spread across 4 g-groups: lanes h, h+16, h+32, h+48)
    float mx = fmaxf(fmaxf(s[0], s[1]), fmaxf(s[2], s[3]));
    mx = fmaxf(mx, __shfl_xor(mx, 16));
    mx = fmaxf(mx, __shfl_xor(mx, 32));
    float e[4], sum = 0.f;
#pragma unroll
    for (int t4 = 0; t4 < 4; ++t4) { e[t4] = __expf(s[t4] - mx); sum += e[t4]; }
    sum += __shfl_xor(sum, 16);
    sum += __shfl_xor(sum, 32);
    const float inv = 1.f / sum;
#pragma unroll
    for (int t4 = 0; t4 < 4; ++t4) sp[wave][h * 20 + g * 4 + t4] = e[t4] * inv;
    __syncthreads();

    // PV: lane (h2 = lane&15, dc = lane>>4) computes o[h2][dc*16 .. +15]
    const int h2 = h, dc = g;
    float o[16];
#pragma unroll
    for (int e2 = 0; e2 < 16; ++e2) o[e2] = 0.f;
#pragma unroll
    for (int t = 0; t < 16; ++t) {
        float pv = sp[wave][h2 * 20 + t];
        uint4 v0 = *(const uint4*)&sq[wave][2][t * 72 + dc * 16];
        uint4 v1 = *(const uint4*)&sq[wave][2][t * 72 + dc * 16 + 8];
        float vf[16]; unpack8(v0, vf); unpack8(v1, vf + 8);
#pragma unroll
        for (int e2 = 0; e2 < 16; ++e2) o[e2] = fmaf(pv, vf[e2], o[e2]);
    }
    u16 ob[16];
#pragma unroll
    for (int e2 = 0; e2 < 16; ++e2) ob[e2] = f2bf(o[e2]);
    uint4* dst = (uint4*)(O + m * 1024 + h2 * 64 + dc * 16);
    dst[0] = ((uint4*)ob)[0];
    dst[1] = ((uint4*)ob)[1];
}

// ---------- launch ----------
extern "C" void kernel_launch(void* const* d_in, const int* in_sizes, int n_in,
                              void* d_out, int out_size, void* d_ws, size_t ws_size,
                              hipStream_t stream) {
    const float* x   = (const float*)d_in[0];
    const float* Wq  = (const float*)d_in[1];
    const float* Wk  = (const float*)d_in[2];
    const float* Wv  = (const float*)d_in[3];
    const float* Wfc = (const float*)d_in[4];
    float* out = (float*)d_out;

    // B=4, S=4096, DM=1024 -> M=16384, K=1024, Nqkv=3072
    const int M = 16384, K = 1024, NQKV = 3072, N2 = 1024;

    char* ws = (char*)d_ws;
    u16* xb    = (u16*)ws;                                  // 33,554,432 B (also O later)
    u16* wqkvb = (u16*)(ws + 33554432);                     //  6,291,456 B
    u16* wfcb  = (u16*)(ws + 33554432 + 6291456);           //  2,097,152 B
    u16* qkv   = (u16*)(ws + 33554432 + 6291456 + 2097152); // 100,663,296 B

    // 4,194,304 (x) + 1,048,576 (weights) = 5,242,880 float4 / 256 = 20480 blocks
    cast_all<<<20480, 256, 0, stream>>>(x, Wq, Wk, Wv, Wfc, xb, wqkvb, wfcb);

    gemm_bt<0><<<dim3(NQKV / BN, M / BM), 256, 0, stream>>>(xb, wqkvb, qkv, M, NQKV, K);

    u16* Ob = xb;   // alias: GEMM1 was the last reader of xb
    attn_kernel<<<M / 4, 256, 0, stream>>>(qkv, Ob);

    gemm_bt<1><<<dim3(N2 / BN, M / BM), 256, 0, stream>>>(Ob, wfcb, out, M, N2, K);
}

// Round 3
// 301.946 us; speedup vs baseline: 1.0895x; 1.0895x over previous
//
#include <hip/hip_runtime.h>

typedef unsigned short u16;
typedef unsigned int u32;
typedef short bf16x8 __attribute__((ext_vector_type(8)));
typedef float f32x4 __attribute__((ext_vector_type(4)));

#define BM 128
#define BN 128

// ---------- helpers ----------
__device__ __forceinline__ u16 f2bf(float f) {
    u32 u = __float_as_uint(f);
    u32 r = (u + 0x7fffu + ((u >> 16) & 1u)) >> 16;   // RNE
    return (u16)r;
}

// async 16B/lane global->LDS (dest = wave-uniform base + lane*16)
__device__ __forceinline__ void gld_lds16(const void* g, void* s) {
    __builtin_amdgcn_global_load_lds(
        (__attribute__((address_space(1))) void*)(g),
        (__attribute__((address_space(3))) void*)(s),
        16, 0, 0);
}

// ---------- merged cast kernel: x (16M f32) + 4 weights (4M f32) -> bf16 ----------
__global__ void cast_all(const float* __restrict__ x,
                         const float* __restrict__ wq, const float* __restrict__ wk,
                         const float* __restrict__ wv, const float* __restrict__ wfc,
                         u16* __restrict__ xb, u16* __restrict__ wqkvb, u16* __restrict__ wfcb) {
    size_t g = (size_t)blockIdx.x * 256 + threadIdx.x;   // float4 index
    const float* s;
    u16* d;
    size_t off;
    if (g < 4194304u) {            // x: 16,777,216 floats = 4,194,304 float4
        s = x; d = xb; off = g;
    } else {
        size_t w = g - 4194304u;   // weights: 4 x 262,144 float4
        int y = (int)(w >> 18);
        off = w & 262143u;
        s = (y == 0) ? wq : (y == 1) ? wk : (y == 2) ? wv : wfc;
        d = (y < 3) ? (wqkvb + (size_t)y * 1048576u) : wfcb;
    }
    float4 v = ((const float4*)s)[off];
    ushort4 o;
    o.x = f2bf(v.x); o.y = f2bf(v.y); o.z = f2bf(v.z); o.w = f2bf(v.w);
    *(ushort4*)(d + off * 4) = o;
}

// ---------- bf16 GEMM: C[M,N] = A[M,K] * B[N,K]^T ----------
// Round-1 form (16x16x32, 4x4 acc/wave): measured 102 us, MfmaUtil 44%,
// SQ_LDS_BANK_CONFLICT = 0. (32x32x16 variant regressed: 4 lanes/chunk ->
// 4-way ds_read conflicts. XOR swizzle is only free at <=2 lanes/chunk.)
template <int STOREF32>
__global__ __launch_bounds__(256, 2)
void gemm_bt(const u16* __restrict__ A, const u16* __restrict__ B,
             void* __restrict__ C, int M, int N, int K) {
    __shared__ __align__(16) u16 As[BM * 64];
    __shared__ __align__(16) u16 Bs[BN * 64];

    const int tid  = threadIdx.x;
    const int lane = tid & 63;
    const int wave = tid >> 6;
    const int wm = wave >> 1, wn = wave & 1;
    const int bm = blockIdx.y * BM;
    const int bn = blockIdx.x * BN;

    const int srow   = lane >> 3;            // row within 8-row staging group
    const int schunk = (lane & 7) ^ srow;    // xor-swizzled source chunk

    f32x4 acc[4][4];
#pragma unroll
    for (int i = 0; i < 4; ++i)
#pragma unroll
        for (int j = 0; j < 4; ++j) acc[i][j] = (f32x4){0.f, 0.f, 0.f, 0.f};

    const int nkt = K >> 6;
    for (int kt = 0; kt < nkt; ++kt) {
        const int k0 = kt << 6;
        __syncthreads();   // prior compute done reading LDS
#pragma unroll
        for (int j = 0; j < 4; ++j) {
            const int r = wave * 32 + j * 8;
            gld_lds16(A + (size_t)(bm + r + srow) * K + k0 + schunk * 8, &As[r * 64]);
            gld_lds16(B + (size_t)(bn + r + srow) * K + k0 + schunk * 8, &Bs[r * 64]);
        }
        __syncthreads();   // compiler drains vmcnt before barrier
#pragma unroll
        for (int kk = 0; kk < 2; ++kk) {
            const int c = kk * 4 + (lane >> 4);
            bf16x8 af[4], bfr[4];
#pragma unroll
            for (int i = 0; i < 4; ++i) {
                int m = wm * 64 + i * 16 + (lane & 15);
                af[i] = *(const bf16x8*)&As[m * 64 + ((c ^ (m & 7)) << 3)];
            }
#pragma unroll
            for (int j = 0; j < 4; ++j) {
                int n = wn * 64 + j * 16 + (lane & 15);
                bfr[j] = *(const bf16x8*)&Bs[n * 64 + ((c ^ (n & 7)) << 3)];
            }
#pragma unroll
            for (int i = 0; i < 4; ++i)
#pragma unroll
                for (int j = 0; j < 4; ++j)
                    acc[i][j] = __builtin_amdgcn_mfma_f32_16x16x32_bf16(
                        af[i], bfr[j], acc[i][j], 0, 0, 0);
        }
    }

    // epilogue: D layout col=lane&15, row=(lane>>4)*4+reg
    const int cr = (lane >> 4) * 4;
    const int cc = lane & 15;
#pragma unroll
    for (int i = 0; i < 4; ++i) {
#pragma unroll
        for (int j = 0; j < 4; ++j) {
            const int row0 = bm + wm * 64 + i * 16 + cr;
            const int col  = bn + wn * 64 + j * 16 + cc;
#pragma unroll
            for (int r = 0; r < 4; ++r) {
                float v = acc[i][j][r];
                size_t idx = (size_t)(row0 + r) * N + col;
                if (STOREF32) ((float*)C)[idx] = v;
                else          ((u16*)C)[idx]   = f2bf(v);
            }
        }
    }
}

// ---------- per-token attention (MFMA): 1 wave = 1 token ----------
// QKV row m: [q(1024) | k(1024) | v(1024)] bf16, 16 heads x 64 dim.
// S^T = K·Q^T  (two 16x16x32 MFMAs over d=64)
//   C-layout: lane holds S[h=lane&15][t=g*4+reg]  (g = lane>>4)
// softmax over t: in-lane over 4 regs + shfl_xor 16,32
// P^T C-layout == B-operand layout -> LDS roundtrip to bf16 sP[h][t]
// O^T = V^T·P^T (4 zero-padded 16x16x32 MFMAs, k=t in [0,16), upper half
//   B-frag = 0; A reads duplicate valid data so no NaN*0)
__global__ __launch_bounds__(256)
void attn_kernel(const u16* __restrict__ QKV, u16* __restrict__ O) {
    __shared__ __align__(16) u16 sQ[4][16 * 80];   // rows padded 64->80 (160B, bank-balanced)
    __shared__ __align__(16) u16 sK[4][16 * 80];
    __shared__ __align__(16) u16 sV[4][64 * 16];   // V^T: [d][t], t-blocks of 8 swizzled by d bit3
    __shared__ __align__(16) u16 sP[4][16 * 16];   // P[h][t] bf16

    const int lane = threadIdx.x & 63;
    const int wave = threadIdx.x >> 6;
    const size_t m = (size_t)blockIdx.x * 4 + wave;
    const u16* base = QKV + m * 3072;

    // ---- stage Q,K: 256 chunks of 8 elems -> [row][80] b128 writes ----
#pragma unroll
    for (int c6 = 0; c6 < 4; ++c6) {
        int chunk = c6 * 64 + lane;          // 0..255
        uint4 v = *(const uint4*)(base + chunk * 8);
        int cc = chunk & 127;
        int row = cc >> 3, pch = cc & 7;
        u16* dst = (chunk < 128) ? sQ[wave] : sK[wave];
        *(uint4*)&dst[row * 80 + pch * 8] = v;
    }
    // ---- stage V transposed: element (t,d) -> sV[d*16 + blk*8 + (t&7)],
    //      blk = (t>>3) ^ ((d>>3)&1)  (block swizzle to spread write banks) ----
#pragma unroll
    for (int c6 = 0; c6 < 2; ++c6) {
        int cc = c6 * 64 + lane;             // 0..127
        int t = cc >> 3, d0 = (cc & 7) * 8;
        uint4 v = *(const uint4*)(base + 2048 + cc * 8);
        u16 e[8]; *(uint4*)e = v;
#pragma unroll
        for (int k = 0; k < 8; ++k) {
            int d = d0 + k;
            int blk = (t >> 3) ^ ((d >> 3) & 1);
            sV[wave][d * 16 + blk * 8 + (t & 7)] = e[k];
        }
    }
    __syncthreads();

    const int ln = lane & 15;   // m/n index within a 16x16 tile
    const int g  = lane >> 4;

    // ---- S^T = K·Q^T : A[m=t][kd], B[n=h][kd], kd = g*8+j (+32 for 2nd) ----
    f32x4 s = (f32x4){0.f, 0.f, 0.f, 0.f};
    {
        bf16x8 a0 = *(const bf16x8*)&sK[wave][ln * 80 + g * 8];
        bf16x8 b0 = *(const bf16x8*)&sQ[wave][ln * 80 + g * 8];
        s = __builtin_amdgcn_mfma_f32_16x16x32_bf16(a0, b0, s, 0, 0, 0);
        bf16x8 a1 = *(const bf16x8*)&sK[wave][ln * 80 + 32 + g * 8];
        bf16x8 b1 = *(const bf16x8*)&sQ[wave][ln * 80 + 32 + g * 8];
        s = __builtin_amdgcn_mfma_f32_16x16x32_bf16(a1, b1, s, 0, 0, 0);
    }
    // lane holds S[h=ln][t=g*4+reg] * (1/8)
    float sv[4];
#pragma unroll
    for (int r = 0; r < 4; ++r) sv[r] = s[r] * 0.125f;

    // ---- softmax over t ----
    float mx = fmaxf(fmaxf(sv[0], sv[1]), fmaxf(sv[2], sv[3]));
    mx = fmaxf(mx, __shfl_xor(mx, 16));
    mx = fmaxf(mx, __shfl_xor(mx, 32));
    float e[4], sum = 0.f;
#pragma unroll
    for (int r = 0; r < 4; ++r) { e[r] = __expf(sv[r] - mx); sum += e[r]; }
    sum += __shfl_xor(sum, 16);
    sum += __shfl_xor(sum, 32);
    const float inv = 1.f / sum;

    // ---- P[h][t] -> LDS bf16 (C-layout feeds B-operand after roundtrip) ----
    ushort4 pb;
    pb.x = f2bf(e[0] * inv); pb.y = f2bf(e[1] * inv);
    pb.z = f2bf(e[2] * inv); pb.w = f2bf(e[3] * inv);
    *(ushort4*)&sP[wave][ln * 16 + g * 4] = pb;
    __syncthreads();

    // ---- O^T = V^T·P^T : B[n=h][k=t] from sP (zero for k>=16) ----
    bf16x8 bl = *(const bf16x8*)&sP[wave][ln * 16 + (g & 1) * 8];
    bf16x8 bz = (bf16x8){0, 0, 0, 0, 0, 0, 0, 0};
    bf16x8 bp = (g < 2) ? bl : bz;

#pragma unroll
    for (int dt = 0; dt < 4; ++dt) {
        int d = dt * 16 + ln;                       // A-frag m index
        int blk = (g & 1) ^ ((d >> 3) & 1);
        bf16x8 av = *(const bf16x8*)&sV[wave][d * 16 + blk * 8];
        f32x4 o = __builtin_amdgcn_mfma_f32_16x16x32_bf16(
            av, bp, (f32x4){0.f, 0.f, 0.f, 0.f}, 0, 0, 0);
        // lane holds O[h=ln][d = dt*16 + g*4 + reg]
        ushort4 ob;
        ob.x = f2bf(o[0]); ob.y = f2bf(o[1]);
        ob.z = f2bf(o[2]); ob.w = f2bf(o[3]);
        *(ushort4*)(O + m * 1024 + ln * 64 + dt * 16 + g * 4) = ob;
    }
}

// ---------- launch ----------
extern "C" void kernel_launch(void* const* d_in, const int* in_sizes, int n_in,
                              void* d_out, int out_size, void* d_ws, size_t ws_size,
                              hipStream_t stream) {
    const float* x   = (const float*)d_in[0];
    const float* Wq  = (const float*)d_in[1];
    const float* Wk  = (const float*)d_in[2];
    const float* Wv  = (const float*)d_in[3];
    const float* Wfc = (const float*)d_in[4];
    float* out = (float*)d_out;

    // B=4, S=4096, DM=1024 -> M=16384, K=1024, Nqkv=3072
    const int M = 16384, K = 1024, NQKV = 3072, N2 = 1024;

    char* ws = (char*)d_ws;
    u16* xb    = (u16*)ws;                                  // 33,554,432 B (also O later)
    u16* wqkvb = (u16*)(ws + 33554432);                     //  6,291,456 B
    u16* wfcb  = (u16*)(ws + 33554432 + 6291456);           //  2,097,152 B
    u16* qkv   = (u16*)(ws + 33554432 + 6291456 + 2097152); // 100,663,296 B

    cast_all<<<20480, 256, 0, stream>>>(x, Wq, Wk, Wv, Wfc, xb, wqkvb, wfcb);

    gemm_bt<0><<<dim3(NQKV / BN, M / BM), 256, 0, stream>>>(xb, wqkvb, qkv, M, NQKV, K);

    u16* Ob = xb;   // alias: GEMM1 was the last reader of xb
    attn_kernel<<<M / 4, 256, 0, stream>>>(qkv, Ob);

    gemm_bt<1><<<dim3(N2 / BN, M / BM), 256, 0, stream>>>(Ob, wfcb, out, M, N2, K);
}

// Round 4
// 296.732 us; speedup vs baseline: 1.1086x; 1.0176x over previous
//
#include <hip/hip_runtime.h>

typedef unsigned short u16;
typedef unsigned int u32;
typedef short bf16x8 __attribute__((ext_vector_type(8)));
typedef float f32x4 __attribute__((ext_vector_type(4)));

#define BM 256
#define BN 128

// ---------- helpers ----------
__device__ __forceinline__ u16 f2bf(float f) {
    u32 u = __float_as_uint(f);
    u32 r = (u + 0x7fffu + ((u >> 16) & 1u)) >> 16;   // RNE
    return (u16)r;
}

// async 16B/lane global->LDS (dest = wave-uniform base + lane*16)
__device__ __forceinline__ void gld_lds16(const void* g, void* s) {
    __builtin_amdgcn_global_load_lds(
        (__attribute__((address_space(1))) void*)(g),
        (__attribute__((address_space(3))) void*)(s),
        16, 0, 0);
}

// ---------- merged cast kernel: x (16M f32) + 4 weights (4M f32) -> bf16 ----------
__global__ void cast_all(const float* __restrict__ x,
                         const float* __restrict__ wq, const float* __restrict__ wk,
                         const float* __restrict__ wv, const float* __restrict__ wfc,
                         u16* __restrict__ xb, u16* __restrict__ wqkvb, u16* __restrict__ wfcb) {
    size_t g = (size_t)blockIdx.x * 256 + threadIdx.x;   // float4 index
    const float* s;
    u16* d;
    size_t off;
    if (g < 4194304u) {            // x: 16,777,216 floats = 4,194,304 float4
        s = x; d = xb; off = g;
    } else {
        size_t w = g - 4194304u;   // weights: 4 x 262,144 float4
        int y = (int)(w >> 18);
        off = w & 262143u;
        s = (y == 0) ? wq : (y == 1) ? wk : (y == 2) ? wv : wfc;
        d = (y < 3) ? (wqkvb + (size_t)y * 1048576u) : wfcb;
    }
    float4 v = ((const float4*)s)[off];
    ushort4 o;
    o.x = f2bf(v.x); o.y = f2bf(v.y); o.z = f2bf(v.z); o.w = f2bf(v.w);
    *(ushort4*)(d + off * 4) = o;
}

// ---------- bf16 GEMM: C[M,N] = A[M,K] * B[N,K]^T ----------
// 256x128 block tile, BK=64, 4 waves (2x2), per-wave tile 128x64 (8x4 acc of
// 16x16x32). Rationale: LDS-read bytes per MFMA = (m+n)/(m*n); 64x64/wave sat
// at the LDS/MFMA balance point (MfmaUtil 44%); 128x64 cuts LDS reads 25%.
// XOR-swizzled staging (phys_chunk = logical ^ (row&7)) -> 0 bank conflicts
// (frag geometry unchanged: 16 lanes x 4 chunk phases, 2 lanes/bank).
template <int STOREF32>
__global__ __launch_bounds__(256, 2)
void gemm_bt(const u16* __restrict__ A, const u16* __restrict__ B,
             void* __restrict__ C, int M, int N, int K) {
    __shared__ __align__(16) u16 As[BM * 64];   // 32 KB
    __shared__ __align__(16) u16 Bs[BN * 64];   // 16 KB

    const int tid  = threadIdx.x;
    const int lane = tid & 63;
    const int wave = tid >> 6;
    const int wm = wave >> 1, wn = wave & 1;
    const int bm = blockIdx.y * BM;
    const int bn = blockIdx.x * BN;

    const int srow   = lane >> 3;            // row within 8-row staging group
    const int schunk = (lane & 7) ^ srow;    // xor-swizzled source chunk

    f32x4 acc[8][4];
#pragma unroll
    for (int i = 0; i < 8; ++i)
#pragma unroll
        for (int j = 0; j < 4; ++j) acc[i][j] = (f32x4){0.f, 0.f, 0.f, 0.f};

    const int nkt = K >> 6;
    for (int kt = 0; kt < nkt; ++kt) {
        const int k0 = kt << 6;
        __syncthreads();   // prior compute done reading LDS
#pragma unroll
        for (int j = 0; j < 8; ++j) {        // A: 256 rows, 32 rows/round
            const int r = j * 32 + wave * 8;
            gld_lds16(A + (size_t)(bm + r + srow) * K + k0 + schunk * 8, &As[r * 64]);
        }
#pragma unroll
        for (int j = 0; j < 4; ++j) {        // B: 128 rows
            const int r = j * 32 + wave * 8;
            gld_lds16(B + (size_t)(bn + r + srow) * K + k0 + schunk * 8, &Bs[r * 64]);
        }
        __syncthreads();   // compiler drains vmcnt before barrier
#pragma unroll
        for (int kk = 0; kk < 2; ++kk) {
            const int c = kk * 4 + (lane >> 4);
            bf16x8 af[8], bfr[4];
#pragma unroll
            for (int i = 0; i < 8; ++i) {
                int m = wm * 128 + i * 16 + (lane & 15);
                af[i] = *(const bf16x8*)&As[m * 64 + ((c ^ (m & 7)) << 3)];
            }
#pragma unroll
            for (int j = 0; j < 4; ++j) {
                int n = wn * 64 + j * 16 + (lane & 15);
                bfr[j] = *(const bf16x8*)&Bs[n * 64 + ((c ^ (n & 7)) << 3)];
            }
#pragma unroll
            for (int i = 0; i < 8; ++i)
#pragma unroll
                for (int j = 0; j < 4; ++j)
                    acc[i][j] = __builtin_amdgcn_mfma_f32_16x16x32_bf16(
                        af[i], bfr[j], acc[i][j], 0, 0, 0);
        }
    }

    // epilogue: D layout col=lane&15, row=(lane>>4)*4+reg
    const int cr = (lane >> 4) * 4;
    const int cc = lane & 15;
#pragma unroll
    for (int i = 0; i < 8; ++i) {
#pragma unroll
        for (int j = 0; j < 4; ++j) {
            const int row0 = bm + wm * 128 + i * 16 + cr;
            const int col  = bn + wn * 64 + j * 16 + cc;
#pragma unroll
            for (int r = 0; r < 4; ++r) {
                float v = acc[i][j][r];
                size_t idx = (size_t)(row0 + r) * N + col;
                if (STOREF32) ((float*)C)[idx] = v;
                else          ((u16*)C)[idx]   = f2bf(v);
            }
        }
    }
}

// ---------- per-token attention (MFMA): 1 wave = 1 token ----------
// QKV row m: [q(1024) | k(1024) | v(1024)] bf16, 16 heads x 64 dim.
// S^T = K·Q^T  (two 16x16x32 MFMAs over d=64)
//   C-layout: lane holds S[h=lane&15][t=g*4+reg]  (g = lane>>4)
// softmax over t: in-lane over 4 regs + shfl_xor 16,32
// P^T C-layout == B-operand layout -> LDS roundtrip to bf16 sP[h][t]
// O^T = V^T·P^T (4 zero-padded 16x16x32 MFMAs, k=t in [0,16), upper half
//   B-frag = 0; A reads duplicate valid data so no NaN*0)
__global__ __launch_bounds__(256)
void attn_kernel(const u16* __restrict__ QKV, u16* __restrict__ O) {
    __shared__ __align__(16) u16 sQ[4][16 * 80];   // rows padded 64->80 (160B, bank-balanced)
    __shared__ __align__(16) u16 sK[4][16 * 80];
    __shared__ __align__(16) u16 sV[4][64 * 16];   // V^T: [d][t], t-blocks of 8 swizzled by d bit3
    __shared__ __align__(16) u16 sP[4][16 * 16];   // P[h][t] bf16

    const int lane = threadIdx.x & 63;
    const int wave = threadIdx.x >> 6;
    const size_t m = (size_t)blockIdx.x * 4 + wave;
    const u16* base = QKV + m * 3072;

    // ---- stage Q,K: 256 chunks of 8 elems -> [row][80] b128 writes ----
#pragma unroll
    for (int c6 = 0; c6 < 4; ++c6) {
        int chunk = c6 * 64 + lane;          // 0..255
        uint4 v = *(const uint4*)(base + chunk * 8);
        int cc = chunk & 127;
        int row = cc >> 3, pch = cc & 7;
        u16* dst = (chunk < 128) ? sQ[wave] : sK[wave];
        *(uint4*)&dst[row * 80 + pch * 8] = v;
    }
    // ---- stage V transposed: element (t,d) -> sV[d*16 + blk*8 + (t&7)],
    //      blk = (t>>3) ^ ((d>>3)&1)  (block swizzle to spread write banks) ----
#pragma unroll
    for (int c6 = 0; c6 < 2; ++c6) {
        int cc = c6 * 64 + lane;             // 0..127
        int t = cc >> 3, d0 = (cc & 7) * 8;
        uint4 v = *(const uint4*)(base + 2048 + cc * 8);
        u16 e[8]; *(uint4*)e = v;
#pragma unroll
        for (int k = 0; k < 8; ++k) {
            int d = d0 + k;
            int blk = (t >> 3) ^ ((d >> 3) & 1);
            sV[wave][d * 16 + blk * 8 + (t & 7)] = e[k];
        }
    }
    __syncthreads();

    const int ln = lane & 15;   // m/n index within a 16x16 tile
    const int g  = lane >> 4;

    // ---- S^T = K·Q^T : A[m=t][kd], B[n=h][kd], kd = g*8+j (+32 for 2nd) ----
    f32x4 s = (f32x4){0.f, 0.f, 0.f, 0.f};
    {
        bf16x8 a0 = *(const bf16x8*)&sK[wave][ln * 80 + g * 8];
        bf16x8 b0 = *(const bf16x8*)&sQ[wave][ln * 80 + g * 8];
        s = __builtin_amdgcn_mfma_f32_16x16x32_bf16(a0, b0, s, 0, 0, 0);
        bf16x8 a1 = *(const bf16x8*)&sK[wave][ln * 80 + 32 + g * 8];
        bf16x8 b1 = *(const bf16x8*)&sQ[wave][ln * 80 + 32 + g * 8];
        s = __builtin_amdgcn_mfma_f32_16x16x32_bf16(a1, b1, s, 0, 0, 0);
    }
    // lane holds S[h=ln][t=g*4+reg] * (1/8)
    float sv[4];
#pragma unroll
    for (int r = 0; r < 4; ++r) sv[r] = s[r] * 0.125f;

    // ---- softmax over t ----
    float mx = fmaxf(fmaxf(sv[0], sv[1]), fmaxf(sv[2], sv[3]));
    mx = fmaxf(mx, __shfl_xor(mx, 16));
    mx = fmaxf(mx, __shfl_xor(mx, 32));
    float e[4], sum = 0.f;
#pragma unroll
    for (int r = 0; r < 4; ++r) { e[r] = __expf(sv[r] - mx); sum += e[r]; }
    sum += __shfl_xor(sum, 16);
    sum += __shfl_xor(sum, 32);
    const float inv = 1.f / sum;

    // ---- P[h][t] -> LDS bf16 (C-layout feeds B-operand after roundtrip) ----
    ushort4 pb;
    pb.x = f2bf(e[0] * inv); pb.y = f2bf(e[1] * inv);
    pb.z = f2bf(e[2] * inv); pb.w = f2bf(e[3] * inv);
    *(ushort4*)&sP[wave][ln * 16 + g * 4] = pb;
    __syncthreads();

    // ---- O^T = V^T·P^T : B[n=h][k=t] from sP (zero for k>=16) ----
    bf16x8 bl = *(const bf16x8*)&sP[wave][ln * 16 + (g & 1) * 8];
    bf16x8 bz = (bf16x8){0, 0, 0, 0, 0, 0, 0, 0};
    bf16x8 bp = (g < 2) ? bl : bz;

#pragma unroll
    for (int dt = 0; dt < 4; ++dt) {
        int d = dt * 16 + ln;                       // A-frag m index
        int blk = (g & 1) ^ ((d >> 3) & 1);
        bf16x8 av = *(const bf16x8*)&sV[wave][d * 16 + blk * 8];
        f32x4 o = __builtin_amdgcn_mfma_f32_16x16x32_bf16(
            av, bp, (f32x4){0.f, 0.f, 0.f, 0.f}, 0, 0, 0);
        // lane holds O[h=ln][d = dt*16 + g*4 + reg]
        ushort4 ob;
        ob.x = f2bf(o[0]); ob.y = f2bf(o[1]);
        ob.z = f2bf(o[2]); ob.w = f2bf(o[3]);
        *(ushort4*)(O + m * 1024 + ln * 64 + dt * 16 + g * 4) = ob;
    }
}

// ---------- launch ----------
extern "C" void kernel_launch(void* const* d_in, const int* in_sizes, int n_in,
                              void* d_out, int out_size, void* d_ws, size_t ws_size,
                              hipStream_t stream) {
    const float* x   = (const float*)d_in[0];
    const float* Wq  = (const float*)d_in[1];
    const float* Wk  = (const float*)d_in[2];
    const float* Wv  = (const float*)d_in[3];
    const float* Wfc = (const float*)d_in[4];
    float* out = (float*)d_out;

    // B=4, S=4096, DM=1024 -> M=16384, K=1024, Nqkv=3072
    const int M = 16384, K = 1024, NQKV = 3072, N2 = 1024;

    char* ws = (char*)d_ws;
    u16* xb    = (u16*)ws;                                  // 33,554,432 B (also O later)
    u16* wqkvb = (u16*)(ws + 33554432);                     //  6,291,456 B
    u16* wfcb  = (u16*)(ws + 33554432 + 6291456);           //  2,097,152 B
    u16* qkv   = (u16*)(ws + 33554432 + 6291456 + 2097152); // 100,663,296 B

    cast_all<<<20480, 256, 0, stream>>>(x, Wq, Wk, Wv, Wfc, xb, wqkvb, wfcb);

    gemm_bt<0><<<dim3(NQKV / BN, M / BM), 256, 0, stream>>>(xb, wqkvb, qkv, M, NQKV, K);

    u16* Ob = xb;   // alias: GEMM1 was the last reader of xb
    attn_kernel<<<M / 4, 256, 0, stream>>>(qkv, Ob);

    gemm_bt<1><<<dim3(N2 / BN, M / BM), 256, 0, stream>>>(Ob, wfcb, out, M, N2, K);
}

// Round 5
// 296.237 us; speedup vs baseline: 1.1105x; 1.0017x over previous
//
#include <hip/hip_runtime.h>

typedef unsigned short u16;
typedef unsigned int u32;
typedef short bf16x8 __attribute__((ext_vector_type(8)));
typedef float f32x4 __attribute__((ext_vector_type(4)));

#define BN 128

// ---------- helpers ----------
__device__ __forceinline__ u16 f2bf(float f) {
    u32 u = __float_as_uint(f);
    u32 r = (u + 0x7fffu + ((u >> 16) & 1u)) >> 16;   // RNE
    return (u16)r;
}

// async 16B/lane global->LDS (dest = wave-uniform base + lane*16)
__device__ __forceinline__ void gld_lds16(const void* g, void* s) {
    __builtin_amdgcn_global_load_lds(
        (__attribute__((address_space(1))) void*)(g),
        (__attribute__((address_space(3))) void*)(s),
        16, 0, 0);
}

// ---------- merged cast kernel: x (16M f32) + 4 weights (4M f32) -> bf16 ----------
__global__ void cast_all(const float* __restrict__ x,
                         const float* __restrict__ wq, const float* __restrict__ wk,
                         const float* __restrict__ wv, const float* __restrict__ wfc,
                         u16* __restrict__ xb, u16* __restrict__ wqkvb, u16* __restrict__ wfcb) {
    size_t g = (size_t)blockIdx.x * 256 + threadIdx.x;   // float4 index
    const float* s;
    u16* d;
    size_t off;
    if (g < 4194304u) {            // x: 16,777,216 floats = 4,194,304 float4
        s = x; d = xb; off = g;
    } else {
        size_t w = g - 4194304u;   // weights: 4 x 262,144 float4
        int y = (int)(w >> 18);
        off = w & 262143u;
        s = (y == 0) ? wq : (y == 1) ? wk : (y == 2) ? wv : wfc;
        d = (y < 3) ? (wqkvb + (size_t)y * 1048576u) : wfcb;
    }
    float4 v = ((const float4*)s)[off];
    ushort4 o;
    o.x = f2bf(v.x); o.y = f2bf(v.y); o.z = f2bf(v.z); o.w = f2bf(v.w);
    *(ushort4*)(d + off * 4) = o;
}

// ---------- bf16 GEMM: C = A[M,K] * B[N,K]^T ----------
// BMT=128: round-3 config — measured 103 us, MfmaUtil 44%, 0 conflicts.
//   (BMT=256 for GEMM1 regressed: occupancy 3->2 blocks/CU exposes the
//    barrier-drain stall. GEMM1 sits on the m97-structure plateau.)
// BMT=256 kept for GEMM2 only (write-heavy, 512 blocks; round-4 data showed
//   ~18 us improvement vs BM=128 there).
// MODE 0: u16 split store — col<2048 -> C0 (QK scratch, row stride 2048),
//         col>=2048 -> C1 (V buffer, row stride 1024). Block-uniform branch.
// MODE 1: fp32 store to C0, row stride N.
template <int BMT, int MODE>
__global__ __launch_bounds__(256, 2)
void gemm_bt(const u16* __restrict__ A, const u16* __restrict__ B,
             void* __restrict__ C0, void* __restrict__ C1, int M, int N, int K) {
    constexpr int WMT = BMT / 32;              // 16-row m-tiles per wave
    __shared__ __align__(16) u16 As[BMT * 64];
    __shared__ __align__(16) u16 Bs[BN * 64];

    const int tid  = threadIdx.x;
    const int lane = tid & 63;
    const int wave = tid >> 6;
    const int wm = wave >> 1, wn = wave & 1;
    const int bm = blockIdx.y * BMT;
    const int bn = blockIdx.x * BN;

    const int srow   = lane >> 3;            // row within 8-row staging group
    const int schunk = (lane & 7) ^ srow;    // xor-swizzled source chunk

    f32x4 acc[WMT][4];
#pragma unroll
    for (int i = 0; i < WMT; ++i)
#pragma unroll
        for (int j = 0; j < 4; ++j) acc[i][j] = (f32x4){0.f, 0.f, 0.f, 0.f};

    const int nkt = K >> 6;
    for (int kt = 0; kt < nkt; ++kt) {
        const int k0 = kt << 6;
        __syncthreads();   // prior compute done reading LDS
#pragma unroll
        for (int j = 0; j < WMT; ++j) {      // A: BMT rows, 32 rows/round
            const int r = j * 32 + wave * 8;
            gld_lds16(A + (size_t)(bm + r + srow) * K + k0 + schunk * 8, &As[r * 64]);
        }
#pragma unroll
        for (int j = 0; j < 4; ++j) {        // B: 128 rows
            const int r = j * 32 + wave * 8;
            gld_lds16(B + (size_t)(bn + r + srow) * K + k0 + schunk * 8, &Bs[r * 64]);
        }
        __syncthreads();   // compiler drains vmcnt before barrier
#pragma unroll
        for (int kk = 0; kk < 2; ++kk) {
            const int c = kk * 4 + (lane >> 4);
            bf16x8 af[WMT], bfr[4];
#pragma unroll
            for (int i = 0; i < WMT; ++i) {
                int m = wm * (WMT * 16) + i * 16 + (lane & 15);
                af[i] = *(const bf16x8*)&As[m * 64 + ((c ^ (m & 7)) << 3)];
            }
#pragma unroll
            for (int j = 0; j < 4; ++j) {
                int n = wn * 64 + j * 16 + (lane & 15);
                bfr[j] = *(const bf16x8*)&Bs[n * 64 + ((c ^ (n & 7)) << 3)];
            }
#pragma unroll
            for (int i = 0; i < WMT; ++i)
#pragma unroll
                for (int j = 0; j < 4; ++j)
                    acc[i][j] = __builtin_amdgcn_mfma_f32_16x16x32_bf16(
                        af[i], bfr[j], acc[i][j], 0, 0, 0);
        }
    }

    // epilogue: D layout col=lane&15, row=(lane>>4)*4+reg
    const int cr = (lane >> 4) * 4;
    const int cc = lane & 15;
#pragma unroll
    for (int i = 0; i < WMT; ++i) {
#pragma unroll
        for (int j = 0; j < 4; ++j) {
            const int row0 = bm + wm * (WMT * 16) + i * 16 + cr;
            const int col  = bn + wn * 64 + j * 16 + cc;
#pragma unroll
            for (int r = 0; r < 4; ++r) {
                float v = acc[i][j][r];
                const int row = row0 + r;
                if (MODE == 0) {
                    if (col < 2048)
                        ((u16*)C0)[(size_t)row * 2048 + col] = f2bf(v);
                    else
                        ((u16*)C1)[(size_t)row * 1024 + (col - 2048)] = f2bf(v);
                } else {
                    ((float*)C0)[(size_t)row * N + col] = v;
                }
            }
        }
    }
}

// ---------- per-token attention (MFMA): 1 wave = 1 token ----------
// QK row m: [q(1024) | k(1024)] bf16 (in d_out scratch), V row m: [v(1024)].
// S^T = K·Q^T (two 16x16x32 MFMAs), softmax over t, O^T = V^T·P^T.
__global__ __launch_bounds__(256)
void attn_kernel(const u16* __restrict__ QK, const u16* __restrict__ V,
                 u16* __restrict__ O) {
    __shared__ __align__(16) u16 sQ[4][16 * 80];   // rows padded 64->80
    __shared__ __align__(16) u16 sK[4][16 * 80];
    __shared__ __align__(16) u16 sV[4][64 * 16];   // V^T: [d][t], blk swizzle
    __shared__ __align__(16) u16 sP[4][16 * 16];   // P[h][t] bf16

    const int lane = threadIdx.x & 63;
    const int wave = threadIdx.x >> 6;
    const size_t m = (size_t)blockIdx.x * 4 + wave;
    const u16* bqk = QK + m * 2048;
    const u16* bv  = V + m * 1024;

    // ---- stage Q,K: 256 chunks of 8 elems -> [row][80] b128 writes ----
#pragma unroll
    for (int c6 = 0; c6 < 4; ++c6) {
        int chunk = c6 * 64 + lane;          // 0..255
        uint4 v = *(const uint4*)(bqk + chunk * 8);
        int cc = chunk & 127;
        int row = cc >> 3, pch = cc & 7;
        u16* dst = (chunk < 128) ? sQ[wave] : sK[wave];
        *(uint4*)&dst[row * 80 + pch * 8] = v;
    }
    // ---- stage V transposed: (t,d) -> sV[d*16 + blk*8 + (t&7)],
    //      blk = (t>>3) ^ ((d>>3)&1) ----
#pragma unroll
    for (int c6 = 0; c6 < 2; ++c6) {
        int cc = c6 * 64 + lane;             // 0..127
        int t = cc >> 3, d0 = (cc & 7) * 8;
        uint4 v = *(const uint4*)(bv + cc * 8);
        u16 e[8]; *(uint4*)e = v;
#pragma unroll
        for (int k = 0; k < 8; ++k) {
            int d = d0 + k;
            int blk = (t >> 3) ^ ((d >> 3) & 1);
            sV[wave][d * 16 + blk * 8 + (t & 7)] = e[k];
        }
    }
    __syncthreads();

    const int ln = lane & 15;
    const int g  = lane >> 4;

    // ---- S^T = K·Q^T ----
    f32x4 s = (f32x4){0.f, 0.f, 0.f, 0.f};
    {
        bf16x8 a0 = *(const bf16x8*)&sK[wave][ln * 80 + g * 8];
        bf16x8 b0 = *(const bf16x8*)&sQ[wave][ln * 80 + g * 8];
        s = __builtin_amdgcn_mfma_f32_16x16x32_bf16(a0, b0, s, 0, 0, 0);
        bf16x8 a1 = *(const bf16x8*)&sK[wave][ln * 80 + 32 + g * 8];
        bf16x8 b1 = *(const bf16x8*)&sQ[wave][ln * 80 + 32 + g * 8];
        s = __builtin_amdgcn_mfma_f32_16x16x32_bf16(a1, b1, s, 0, 0, 0);
    }
    float sv[4];
#pragma unroll
    for (int r = 0; r < 4; ++r) sv[r] = s[r] * 0.125f;

    // ---- softmax over t ----
    float mx = fmaxf(fmaxf(sv[0], sv[1]), fmaxf(sv[2], sv[3]));
    mx = fmaxf(mx, __shfl_xor(mx, 16));
    mx = fmaxf(mx, __shfl_xor(mx, 32));
    float e[4], sum = 0.f;
#pragma unroll
    for (int r = 0; r < 4; ++r) { e[r] = __expf(sv[r] - mx); sum += e[r]; }
    sum += __shfl_xor(sum, 16);
    sum += __shfl_xor(sum, 32);
    const float inv = 1.f / sum;

    // ---- P[h][t] -> LDS bf16 ----
    ushort4 pb;
    pb.x = f2bf(e[0] * inv); pb.y = f2bf(e[1] * inv);
    pb.z = f2bf(e[2] * inv); pb.w = f2bf(e[3] * inv);
    *(ushort4*)&sP[wave][ln * 16 + g * 4] = pb;
    __syncthreads();

    // ---- O^T = V^T·P^T (zero-padded k) ----
    bf16x8 bl = *(const bf16x8*)&sP[wave][ln * 16 + (g & 1) * 8];
    bf16x8 bz = (bf16x8){0, 0, 0, 0, 0, 0, 0, 0};
    bf16x8 bp = (g < 2) ? bl : bz;

#pragma unroll
    for (int dt = 0; dt < 4; ++dt) {
        int d = dt * 16 + ln;
        int blk = (g & 1) ^ ((d >> 3) & 1);
        bf16x8 av = *(const bf16x8*)&sV[wave][d * 16 + blk * 8];
        f32x4 o = __builtin_amdgcn_mfma_f32_16x16x32_bf16(
            av, bp, (f32x4){0.f, 0.f, 0.f, 0.f}, 0, 0, 0);
        ushort4 ob;
        ob.x = f2bf(o[0]); ob.y = f2bf(o[1]);
        ob.z = f2bf(o[2]); ob.w = f2bf(o[3]);
        *(ushort4*)(O + m * 1024 + ln * 64 + dt * 16 + g * 4) = ob;
    }
}

// ---------- launch ----------
extern "C" void kernel_launch(void* const* d_in, const int* in_sizes, int n_in,
                              void* d_out, int out_size, void* d_ws, size_t ws_size,
                              hipStream_t stream) {
    const float* x   = (const float*)d_in[0];
    const float* Wq  = (const float*)d_in[1];
    const float* Wk  = (const float*)d_in[2];
    const float* Wv  = (const float*)d_in[3];
    const float* Wfc = (const float*)d_in[4];

    // B=4, S=4096, DM=1024 -> M=16384, K=1024, Nqkv=3072
    const int M = 16384, K = 1024, NQKV = 3072, N2 = 1024;

    // ws: 72 MB (was 140). Q||K scratch lives in d_out (u16), overwritten by
    // GEMM2's final fp32 store after attn consumed it (stream-ordered).
    char* ws = (char*)d_ws;
    u16* xb    = (u16*)ws;                                  // 33,554,432 B (also O later)
    u16* wqkvb = (u16*)(ws + 33554432);                     //  6,291,456 B
    u16* wfcb  = (u16*)(ws + 33554432 + 6291456);           //  2,097,152 B
    u16* vbuf  = (u16*)(ws + 33554432 + 6291456 + 2097152); // 33,554,432 B
    u16* qkbuf = (u16*)d_out;                               // 64 MB scratch

    cast_all<<<20480, 256, 0, stream>>>(x, Wq, Wk, Wv, Wfc, xb, wqkvb, wfcb);

    gemm_bt<128, 0><<<dim3(NQKV / BN, M / 128), 256, 0, stream>>>(
        xb, wqkvb, qkbuf, vbuf, M, NQKV, K);

    u16* Ob = xb;   // alias: GEMM1 was the last reader of xb
    attn_kernel<<<M / 4, 256, 0, stream>>>(qkbuf, vbuf, Ob);

    gemm_bt<256, 1><<<dim3(N2 / BN, M / 256), 256, 0, stream>>>(
        Ob, wfcb, d_out, nullptr, M, N2, K);
}